// Round 12
// baseline (2883.884 us; speedup 1.0000x reference)
//
#include <hip/hip_runtime.h>

// Problem sizes (fixed)
#define NR 120000   // occupied voxels
#define CI 32
#define CO 64
#define KK 27

// async global->LDS, 16B per lane. LDS dest must be wave-uniform base + lane*16.
#define GLOAD_LDS16(g, l) __builtin_amdgcn_global_load_lds( \
    (const __attribute__((address_space(1))) unsigned int*)(g), \
    (__attribute__((address_space(3))) unsigned int*)(l), 16, 0, 0)

#define FMA4(acc, g, w0, w1, w2, w3) \
    acc.x += g.x * w0.x + g.y * w1.x + g.z * w2.x + g.w * w3.x; \
    acc.y += g.x * w0.y + g.y * w1.y + g.z * w2.y + g.w * w3.y; \
    acc.z += g.x * w0.z + g.y * w1.z + g.z * w2.z + g.w * w3.z; \
    acc.w += g.x * w0.w + g.y * w1.w + g.z * w2.w + g.w * w3.w;

// ---------------------------------------------------------------------------
// K1: conv1 (32->64) + classifier/mask + compaction.
// gs via DMA dbuf (proven). W read DIRECTLY FROM GLOBAL (L1/L2-resident,
// 8KB/k slice) with 2-stage register pipeline -> no Ws LDS, LDS = 32.6 KB,
// 4 blocks/CU. One barrier per k.
// ---------------------------------------------------------------------------
__global__ __launch_bounds__(256, 4)
void k_conv1(const float* __restrict__ xF, const float* __restrict__ gum,
             const int* __restrict__ nbr, const float* __restrict__ Wch,
             const float* __restrict__ bch, const float* __restrict__ Wcls,
             const float* __restrict__ bcls, const float* __restrict__ zbufX,
             float* __restrict__ x1m, int* __restrict__ sids,
             int* __restrict__ cnt, unsigned* __restrict__ mkbits,
             float* __restrict__ outp)
{
    __shared__ float gs[2 * 128 * CI];      // 32 KB
    __shared__ int   sl[128];
    __shared__ unsigned mwords[4];
    __shared__ int   scnt, sbase;

    const int t    = threadIdx.x;
    const int dq   = t & 15;
    const int rq   = t >> 4;
    const int rq7  = rq & 7;
    const int dq4  = dq * 4;
    const int sr   = t >> 3;   // staging row within 32-row chunk
    const int sq   = t & 7;    // staging quad
    const int row0 = blockIdx.x * 128;

    if (t == 0) scnt = 0;
    if (t < 4) mwords[t] = 0u;

    // --- prologue: ids(k=0), DMA k=0, ids(k=1) ---
    int jr[4];
#pragma unroll
    for (int pp = 0; pp < 4; ++pp) {
        int i = row0 + pp * 32 + sr;
        jr[pp] = (i < NR) ? nbr[i * KK] : NR;
    }
#pragma unroll
    for (int pp = 0; pp < 4; ++pp) {
        int r = pp * 32 + sr;
        const float* gsrc = (jr[pp] < NR) ? (xF + (size_t)jr[pp] * CI)
                                          : (zbufX + (r & 63) * CI);
        GLOAD_LDS16(gsrc + ((sq ^ (r & 7)) << 2), &gs[(pp * 256 + t) * 4]);
    }
#pragma unroll
    for (int pp = 0; pp < 4; ++pp) {
        int i = row0 + pp * 32 + sr;
        jr[pp] = (i < NR) ? nbr[i * KK + 1] : NR;
    }

    const float4 bq = ((const float4*)bch)[dq];
    float4 acc[8];
#pragma unroll
    for (int rp = 0; rp < 8; ++rp) acc[rp] = bq;

    float wcA[4], wcB[4];
#pragma unroll
    for (int c = 0; c < 4; ++c) {
        wcA[c] = Wcls[(dq4 + c) * 2];
        wcB[c] = Wcls[(dq4 + c) * 2 + 1];
    }
    const float b0 = bcls[0], b1 = bcls[1];

    int gso = 0;
    __syncthreads();   // gs buf0 ready

#pragma unroll 1
    for (int k = 0; k < KK; ++k) {
        if (k < KK - 1) {
            // DMA next tile into other buffer (hides under compute)
#pragma unroll
            for (int pp = 0; pp < 4; ++pp) {
                int r = pp * 32 + sr;
                const float* gsrc = (jr[pp] < NR) ? (xF + (size_t)jr[pp] * CI)
                                                  : (zbufX + (r & 63) * CI);
                GLOAD_LDS16(gsrc + ((sq ^ (r & 7)) << 2),
                            &gs[(gso ^ (128 * CI)) + (pp * 256 + t) * 4]);
            }
        }
        if (k < KK - 2) {
#pragma unroll
            for (int pp = 0; pp < 4; ++pp) {
                int i = row0 + pp * 32 + sr;
                jr[pp] = (i < NR) ? nbr[i * KK + k + 2] : NR;
            }
        }
        // compute k: g from LDS, w from GLOBAL (2-stage reg pipeline)
        const float* gsb = &gs[gso];
        const float* Wg  = Wch + (size_t)k * CI * CO;
        float4 wa0 = *(const float4*)(Wg + 0 * CO + dq4);
        float4 wa1 = *(const float4*)(Wg + 1 * CO + dq4);
        float4 wa2 = *(const float4*)(Wg + 2 * CO + dq4);
        float4 wa3 = *(const float4*)(Wg + 3 * CO + dq4);
#pragma unroll
        for (int cq = 0; cq < 8; cq += 2) {
            float4 wb0 = *(const float4*)(Wg + ((cq + 1) * 4 + 0) * CO + dq4);
            float4 wb1 = *(const float4*)(Wg + ((cq + 1) * 4 + 1) * CO + dq4);
            float4 wb2 = *(const float4*)(Wg + ((cq + 1) * 4 + 2) * CO + dq4);
            float4 wb3 = *(const float4*)(Wg + ((cq + 1) * 4 + 3) * CO + dq4);
            {
                const int cs = ((cq ^ rq7) << 2);
#pragma unroll
                for (int rp = 0; rp < 8; ++rp) {
                    float4 g = *(const float4*)&gsb[(rp * 16 + rq) * CI + cs];
                    FMA4(acc[rp], g, wa0, wa1, wa2, wa3)
                }
            }
            if (cq + 2 < 8) {
                wa0 = *(const float4*)(Wg + ((cq + 2) * 4 + 0) * CO + dq4);
                wa1 = *(const float4*)(Wg + ((cq + 2) * 4 + 1) * CO + dq4);
                wa2 = *(const float4*)(Wg + ((cq + 2) * 4 + 2) * CO + dq4);
                wa3 = *(const float4*)(Wg + ((cq + 2) * 4 + 3) * CO + dq4);
            }
            {
                const int cs = (((cq + 1) ^ rq7) << 2);
#pragma unroll
                for (int rp = 0; rp < 8; ++rp) {
                    float4 g = *(const float4*)&gsb[(rp * 16 + rq) * CI + cs];
                    FMA4(acc[rp], g, wb0, wb1, wb2, wb3)
                }
            }
        }
        __syncthreads();   // drains DMA; orders buffer swap
        gso ^= (128 * CI);
    }

    // epilogue: classifier (16-lane shuffle reduce), mask, writes
#pragma unroll
    for (int rp = 0; rp < 8; ++rp) {
        float4 a = acc[rp];
        float p0 = a.x * wcA[0] + a.y * wcA[1] + a.z * wcA[2] + a.w * wcA[3];
        float p1 = a.x * wcB[0] + a.y * wcB[1] + a.z * wcB[2] + a.w * wcB[3];
#pragma unroll
        for (int off = 1; off < 16; off <<= 1) {
            p0 += __shfl_xor(p0, off, 64);
            p1 += __shfl_xor(p1, off, 64);
        }
        int i = row0 + rp * 16 + rq;
        if (i < NR) {
            float z0 = p0 + b0 + gum[2 * i];
            float z1 = p1 + b1 + gum[2 * i + 1];
            bool m = (z0 >= z1);   // argmax tie -> index 0 -> strong
            ((float4*)(outp + (size_t)i * CO))[dq] =
                make_float4(2.f * a.x, 2.f * a.y, 2.f * a.z, 2.f * a.w);
            float4 xm = m ? a : make_float4(0.f, 0.f, 0.f, 0.f);
            ((float4*)(x1m + (size_t)i * CO))[dq] = xm;
            if (dq == 0 && m) {
                int lr = rp * 16 + rq;
                atomicOr(&mwords[lr >> 5], 1u << (lr & 31));
                int pos = atomicAdd(&scnt, 1); sl[pos] = i;
            }
        }
    }
    __syncthreads();
    if (t < 4) mkbits[(row0 >> 5) + t] = mwords[t];
    if (t == 0) sbase = atomicAdd(cnt, scnt);
    __syncthreads();
    if (t < scnt) sids[sbase + t] = sl[t];
}

// ---------------------------------------------------------------------------
// K2: conv2 (64->64) over compacted strong rows. Same template: gs via DMA
// dbuf (bitmask-predicated, spread-zero redirect), W direct from global
// (16KB/k slice, L1/L2-resident) with 2-stage reg pipeline. LDS = 32 KB ->
// 4 blocks/CU. One barrier per k.
// ---------------------------------------------------------------------------
__global__ __launch_bounds__(256, 4)
void k_conv2(const float* __restrict__ x1m, const int* __restrict__ nbr,
             const float* __restrict__ Wdw, const float* __restrict__ bdw,
             const int* __restrict__ sids, const int* __restrict__ cnt,
             const unsigned* __restrict__ mkbits, const float* __restrict__ zbuf1,
             float* __restrict__ outp)
{
    const int nstrong = *cnt;
    const int row0 = blockIdx.x * 64;
    if (row0 >= nstrong) return;

    __shared__ float gs[2][64 * CO];   // 32 KB

    const int t   = threadIdx.x;
    const int dq  = t & 15;
    const int rq  = t >> 4;
    const int dq4 = dq * 4;

    int ssid[4];
#pragma unroll
    for (int p = 0; p < 4; ++p) {
        int rr = row0 + p * 16 + rq;
        ssid[p] = (rr < nstrong) ? sids[rr] : -1;
    }

    // --- prologue: ids(k=0)+mask, DMA k=0, ids(k=1)+mask ---
    int jn[4]; unsigned mw[4];
#pragma unroll
    for (int p = 0; p < 4; ++p)
        jn[p] = (ssid[p] >= 0) ? nbr[ssid[p] * KK] : NR;
#pragma unroll
    for (int p = 0; p < 4; ++p) mw[p] = mkbits[jn[p] >> 5];
#pragma unroll
    for (int p = 0; p < 4; ++p) {
        int r = p * 16 + rq;
        bool s = (mw[p] >> (jn[p] & 31)) & 1u;
        const float* gsrc = s ? (x1m + (size_t)jn[p] * CO) : (zbuf1 + r * CO);
        GLOAD_LDS16(gsrc + ((dq ^ rq) << 2), &gs[0][(p * 256 + t) * 4]);
    }
#pragma unroll
    for (int p = 0; p < 4; ++p)
        jn[p] = (ssid[p] >= 0) ? nbr[ssid[p] * KK + 1] : NR;
#pragma unroll
    for (int p = 0; p < 4; ++p) mw[p] = mkbits[jn[p] >> 5];

    float4 acc[4];
#pragma unroll
    for (int rp = 0; rp < 4; ++rp) acc[rp] = make_float4(0.f, 0.f, 0.f, 0.f);

    int gso = 0;
    __syncthreads();   // gs[0] DMA drained

#pragma unroll 1
    for (int k = 0; k < KK; ++k) {
        if (k < KK - 1) {
            // DMA next tile into other gs buffer (hides under compute)
#pragma unroll
            for (int p = 0; p < 4; ++p) {
                int r = p * 16 + rq;
                bool s = (mw[p] >> (jn[p] & 31)) & 1u;
                const float* gsrc = s ? (x1m + (size_t)jn[p] * CO)
                                      : (zbuf1 + r * CO);
                GLOAD_LDS16(gsrc + ((dq ^ rq) << 2),
                            &gs[gso ^ 1][(p * 256 + t) * 4]);
            }
        }
        if (k < KK - 2) {
#pragma unroll
            for (int p = 0; p < 4; ++p)
                jn[p] = (ssid[p] >= 0) ? nbr[ssid[p] * KK + k + 2] : NR;
#pragma unroll
            for (int p = 0; p < 4; ++p) mw[p] = mkbits[jn[p] >> 5];
        }
        // compute k: g from LDS, w from GLOBAL (2-stage reg pipeline)
        const float* gsb = &gs[gso][0];
        const float* Wg  = Wdw + (size_t)k * CO * CO;
        float4 wa0 = *(const float4*)(Wg + 0 * CO + dq4);
        float4 wa1 = *(const float4*)(Wg + 1 * CO + dq4);
        float4 wa2 = *(const float4*)(Wg + 2 * CO + dq4);
        float4 wa3 = *(const float4*)(Wg + 3 * CO + dq4);
#pragma unroll
        for (int cq = 0; cq < 16; cq += 2) {
            float4 wb0 = *(const float4*)(Wg + ((cq + 1) * 4 + 0) * CO + dq4);
            float4 wb1 = *(const float4*)(Wg + ((cq + 1) * 4 + 1) * CO + dq4);
            float4 wb2 = *(const float4*)(Wg + ((cq + 1) * 4 + 2) * CO + dq4);
            float4 wb3 = *(const float4*)(Wg + ((cq + 1) * 4 + 3) * CO + dq4);
            {
                const int cs = ((cq ^ rq) & 15) << 2;
#pragma unroll
                for (int rp = 0; rp < 4; ++rp) {
                    float4 g = *(const float4*)&gsb[(rp * 16 + rq) * CO + cs];
                    FMA4(acc[rp], g, wa0, wa1, wa2, wa3)
                }
            }
            if (cq + 2 < 16) {
                wa0 = *(const float4*)(Wg + ((cq + 2) * 4 + 0) * CO + dq4);
                wa1 = *(const float4*)(Wg + ((cq + 2) * 4 + 1) * CO + dq4);
                wa2 = *(const float4*)(Wg + ((cq + 2) * 4 + 2) * CO + dq4);
                wa3 = *(const float4*)(Wg + ((cq + 2) * 4 + 3) * CO + dq4);
            }
            {
                const int cs = (((cq + 1) ^ rq) & 15) << 2;
#pragma unroll
                for (int rp = 0; rp < 4; ++rp) {
                    float4 g = *(const float4*)&gsb[(rp * 16 + rq) * CO + cs];
                    FMA4(acc[rp], g, wb0, wb1, wb2, wb3)
                }
            }
        }
        __syncthreads();   // drains DMA; orders buffer swap
        gso ^= 1;
    }

    const float4 bq = ((const float4*)bdw)[dq];
#pragma unroll
    for (int rp = 0; rp < 4; ++rp) {
        int rr = row0 + rp * 16 + rq;
        if (rr < nstrong) {
            int sid = ssid[rp];
            float4 xv = ((const float4*)(x1m + (size_t)sid * CO))[dq];
            float4 a = acc[rp];
            ((float4*)(outp + (size_t)sid * CO))[dq] =
                make_float4(a.x + bq.x + xv.x, a.y + bq.y + xv.y,
                            a.z + bq.z + xv.z, a.w + bq.w + xv.w);
        }
    }
}

// ---------------------------------------------------------------------------
extern "C" void kernel_launch(void* const* d_in, const int* in_sizes, int n_in,
                              void* d_out, int out_size, void* d_ws, size_t ws_size,
                              hipStream_t stream)
{
    const float* xF   = (const float*)d_in[0];
    const float* gum  = (const float*)d_in[1];
    const int*   nbr  = (const int*)d_in[2];
    const float* Wch  = (const float*)d_in[3];
    const float* bch  = (const float*)d_in[4];
    const float* Wcls = (const float*)d_in[5];
    const float* bcls = (const float*)d_in[6];
    const float* Wdw  = (const float*)d_in[7];
    const float* bdw  = (const float*)d_in[8];
    // d_in[9] = th (unused by the forward computation)

    float* outp = (float*)d_out;
    char*  ws   = (char*)d_ws;

    // ws layout (x1m FIRST -> 256B-aligned rows):
    //   [0, 30720000)            x1m   (N*64 f32)
    //   [30720000, 30728192)     zbufX (64 zero rows x 32 f32, 8 KB)
    //   [30728192, 30744576)     zbuf1 (64 zero rows x 64 f32, 16 KB)
    //   [30744576, 30744580)     cnt
    //   [30744704, 30759744)     mkbits (3760 u32, sentinel word included)
    //   [30759744, 31239744)     sids (N i32)
    float*    x1m    = (float*)(ws);
    float*    zbufX  = (float*)(ws + 30720000);
    float*    zbuf1  = (float*)(ws + 30728192);
    int*      cnt    = (int*)(ws + 30744576);
    unsigned* mkbits = (unsigned*)(ws + 30744704);
    int*      sids   = (int*)(ws + 30759744);

    // zero zbufX + zbuf1 + cnt + mkbits in one shot
    hipMemsetAsync(ws + 30720000, 0, 30759744 - 30720000, stream);

    hipLaunchKernelGGL(k_conv1, dim3((NR + 127) / 128), dim3(256), 0, stream,
                       xF, gum, nbr, Wch, bch, Wcls, bcls, zbufX,
                       x1m, sids, cnt, mkbits, outp);
    hipLaunchKernelGGL(k_conv2, dim3((NR + 63) / 64), dim3(256), 0, stream,
                       x1m, nbr, Wdw, bdw, sids, cnt, mkbits, zbuf1, outp);
}